// Round 1
// baseline (199.376 us; speedup 1.0000x reference)
//
#include <hip/hip_runtime.h>

#define NN 100000
#define NE 1600000
#define D 64
#define NBKT 782            // ceil(NN / 128) coarse buckets
#define BKT_SHIFT 7
#define BKT_MASK 127
#define SRC_MASK 0x1FFFF    // src < 100000 < 2^17
#define EPB 2048            // edges per block in P2 (782 blocks -> ~3/CU)
#define NPB ((NE + EPB - 1) / EPB)   // 782 blocks
#define BINCAP 2560         // padded slots per bucket (mean 2048, sd ~45 -> 11 sigma)
#define CSTRIDE 16          // one cursor per 64B cache line (kills same-line atomic serialization)
#define TROWS 16            // rows per block iteration in transform

// float -> bf16 (round-to-nearest-even; inputs finite)
__device__ __forceinline__ unsigned short f2bf(float f) {
    unsigned u = __float_as_uint(f);
    unsigned r = u + 0x7FFF + ((u >> 16) & 1);
    return (unsigned short)(r >> 16);
}

// ---------------- A: h = bf16(feat @ W^T); also seeds p2's cursors ---------
__global__ __launch_bounds__(256) void transform_kernel(const float* __restrict__ feat,
                                                        const float* __restrict__ W,
                                                        unsigned short* __restrict__ hb,
                                                        int* __restrict__ cursor) {
    // seed per-bucket cursors (kernel completes before p2 launches)
    if (blockIdx.x < 4) {
        int i = blockIdx.x * 256 + threadIdx.x;
        if (i < NBKT) cursor[i * CSTRIDE] = i * BINCAP;
    }

    __shared__ float4 rowLds[TROWS][16];
    const int lane = threadIdx.x & 63;
    const int wv   = threadIdx.x >> 6;
    float4 wreg[16];
    const float4* __restrict__ W4 = (const float4*)W;
#pragma unroll
    for (int i = 0; i < 16; ++i) wreg[i] = W4[lane * 16 + i];

    const int nTiles = NN / TROWS;   // 6250 exact
    for (int tile = blockIdx.x; tile < nTiles; tile += gridDim.x) {
        const int rowBase = tile * TROWS;
        rowLds[threadIdx.x >> 4][threadIdx.x & 15] =
            ((const float4*)(feat + (size_t)(rowBase + (threadIdx.x >> 4)) * D))[threadIdx.x & 15];
        __syncthreads();
        float a0 = 0.f, a1 = 0.f, a2 = 0.f, a3 = 0.f;
#pragma unroll
        for (int k4 = 0; k4 < 16; ++k4) {
            const float4 w  = wreg[k4];
            const float4 r0 = rowLds[wv * 4 + 0][k4];
            const float4 r1 = rowLds[wv * 4 + 1][k4];
            const float4 r2 = rowLds[wv * 4 + 2][k4];
            const float4 r3 = rowLds[wv * 4 + 3][k4];
            a0 += r0.x * w.x + r0.y * w.y + r0.z * w.z + r0.w * w.w;
            a1 += r1.x * w.x + r1.y * w.y + r1.z * w.z + r1.w * w.w;
            a2 += r2.x * w.x + r2.y * w.y + r2.z * w.z + r2.w * w.w;
            a3 += r3.x * w.x + r3.y * w.y + r3.z * w.z + r3.w * w.w;
        }
        const size_t ob = (size_t)(rowBase + wv * 4) * D + lane;
        hb[ob]         = f2bf(a0);
        hb[ob + D]     = f2bf(a1);
        hb[ob + 2 * D] = f2bf(a2);
        hb[ob + 3 * D] = f2bf(a3);
        __syncthreads();
    }
}

// ---------------- P2 (single-pass): scatter packed edges into buckets ------
__global__ __launch_bounds__(256) void p2_scatter(const int* __restrict__ src,
                                                  const int* __restrict__ dst,
                                                  int* __restrict__ cursor,
                                                  int* __restrict__ binned) {
    __shared__ int hist[NBKT];
    __shared__ int base[NBKT];
    for (int i = threadIdx.x; i < NBKT; i += 256) hist[i] = 0;
    __syncthreads();

    const int lo = blockIdx.x * EPB;
    int pk[8], rk[8], bk[8];
#pragma unroll
    for (int j = 0; j < 8; ++j) {
        const int e = lo + j * 256 + threadIdx.x;
        if (e < NE) {
            const int dv = dst[e];
            const int sv = src[e];
            bk[j] = dv >> BKT_SHIFT;
            pk[j] = sv | ((dv & BKT_MASK) << 17);
        } else {
            bk[j] = -1; pk[j] = 0;
        }
    }
#pragma unroll
    for (int j = 0; j < 8; ++j)
        if (bk[j] >= 0) rk[j] = atomicAdd(&hist[bk[j]], 1);
    __syncthreads();

    for (int i = threadIdx.x; i < NBKT; i += 256) {
        const int c = hist[i];
        base[i] = c ? atomicAdd(&cursor[i * CSTRIDE], c) : 0;
    }
    __syncthreads();

#pragma unroll
    for (int j = 0; j < 8; ++j)
        if (bk[j] >= 0) binned[base[bk[j]] + rk[j]] = pk[j];
}

// ---------------- bucket_gather v2: counting-sort + register accumulate ----
// Per block (one 128-node bucket): counting-sort the ~2048 packed edges by
// dst-low into per-node contiguous segments in LDS (2K LDS atomics instead of
// 102M).  Then each 16-lane quarter-wave owns one node at a time and
// accumulates its 64 columns as 4 fp32 registers per lane — zero ds_add, zero
// bank-conflict-prone accumulator, and the epilogue is a direct coalesced
// float4 store with bias (old writeback pass fused away).
__global__ __launch_bounds__(256) void bucket_gather(const uint2* __restrict__ hb2,
                                                     const int* __restrict__ binned,
                                                     const int* __restrict__ cursor,
                                                     const float* __restrict__ bias,
                                                     float4* __restrict__ out4) {
    __shared__ int cnt[128];     // per-node in-degree (totals after ranking)
    __shared__ int pre[128];     // inclusive scan of cnt
    __shared__ int sEdge[BINCAP];// src indices, sorted by dst-low
    const int t = threadIdx.x;
    const int b = blockIdx.x;
    if (t < 128) cnt[t] = 0;
    __syncthreads();

    const int gbase = b * BINCAP;
    int sz = cursor[b * CSTRIDE] - gbase;
    if (sz > BINCAP) sz = BINCAP;    // 11-sigma guard

    // ---- rank edges per node (counting sort pass 1) ----
    int pk[10], dd[10], rr[10];      // BINCAP/256 == 10
#pragma unroll
    for (int it = 0; it < 10; ++it) {
        const int e = it * 256 + t;
        if (e < sz) {
            const int p = binned[gbase + e];
            dd[it] = (p >> 17) & BKT_MASK;
            pk[it] = p & SRC_MASK;
            rr[it] = atomicAdd(&cnt[dd[it]], 1);
        } else dd[it] = -1;
    }
    __syncthreads();

    // ---- inclusive scan of cnt[128] (Hillis-Steele) ----
    if (t < 128) pre[t] = cnt[t];
    __syncthreads();
    for (int s = 1; s < 128; s <<= 1) {
        int v = 0;
        if (t < 128 && t >= s) v = pre[t - s];
        __syncthreads();
        if (t < 128) pre[t] += v;
        __syncthreads();
    }

    // ---- scatter into per-node segments: node d owns [pre[d]-cnt[d], pre[d]) ----
#pragma unroll
    for (int it = 0; it < 10; ++it) {
        if (dd[it] >= 0)
            sEdge[pre[dd[it]] - cnt[dd[it]] + rr[it]] = pk[it];
    }
    __syncthreads();

    // ---- accumulate: quarter-wave per node, 4 fp32 cols per lane, unroll 4 ----
    const int q  = t >> 4;           // 16 quarters; quarter q owns nodes q*8..q*8+7
    const int c4 = t & 15;           // 8-byte column group (4 bf16 cols)
    const float4 bv = ((const float4*)bias)[c4];
    for (int i = 0; i < 8; ++i) {
        const int n    = q * 8 + i;
        const int node = b * 128 + n;
        if (node >= NN) break;       // uniform within quarter
        const int end = pre[n];
        int e = end - cnt[n];
        float a00=0.f,a01=0.f,a02=0.f,a03=0.f, a10=0.f,a11=0.f,a12=0.f,a13=0.f;
        float a20=0.f,a21=0.f,a22=0.f,a23=0.f, a30=0.f,a31=0.f,a32=0.f,a33=0.f;
        for (; e + 4 <= end; e += 4) {
            const int s0 = sEdge[e+0], s1 = sEdge[e+1], s2 = sEdge[e+2], s3 = sEdge[e+3];
            const uint2 x0 = hb2[(size_t)s0 * 16 + c4];
            const uint2 x1 = hb2[(size_t)s1 * 16 + c4];
            const uint2 x2 = hb2[(size_t)s2 * 16 + c4];
            const uint2 x3 = hb2[(size_t)s3 * 16 + c4];
            a00 += __uint_as_float(x0.x << 16); a01 += __uint_as_float(x0.x & 0xFFFF0000u);
            a02 += __uint_as_float(x0.y << 16); a03 += __uint_as_float(x0.y & 0xFFFF0000u);
            a10 += __uint_as_float(x1.x << 16); a11 += __uint_as_float(x1.x & 0xFFFF0000u);
            a12 += __uint_as_float(x1.y << 16); a13 += __uint_as_float(x1.y & 0xFFFF0000u);
            a20 += __uint_as_float(x2.x << 16); a21 += __uint_as_float(x2.x & 0xFFFF0000u);
            a22 += __uint_as_float(x2.y << 16); a23 += __uint_as_float(x2.y & 0xFFFF0000u);
            a30 += __uint_as_float(x3.x << 16); a31 += __uint_as_float(x3.x & 0xFFFF0000u);
            a32 += __uint_as_float(x3.y << 16); a33 += __uint_as_float(x3.y & 0xFFFF0000u);
        }
        for (; e < end; ++e) {
            const int s0 = sEdge[e];
            const uint2 x0 = hb2[(size_t)s0 * 16 + c4];
            a00 += __uint_as_float(x0.x << 16); a01 += __uint_as_float(x0.x & 0xFFFF0000u);
            a02 += __uint_as_float(x0.y << 16); a03 += __uint_as_float(x0.y & 0xFFFF0000u);
        }
        float4 v;
        v.x = (a00 + a10) + (a20 + a30) + bv.x;
        v.y = (a01 + a11) + (a21 + a31) + bv.y;
        v.z = (a02 + a12) + (a22 + a32) + bv.z;
        v.w = (a03 + a13) + (a23 + a33) + bv.w;
        out4[(size_t)node * 16 + c4] = v;
    }
}

extern "C" void kernel_launch(void* const* d_in, const int* in_sizes, int n_in,
                              void* d_out, int out_size, void* d_ws, size_t ws_size,
                              hipStream_t stream) {
    const float* feat = (const float*)d_in[0];
    const int*   src  = (const int*)d_in[1];
    const int*   dst  = (const int*)d_in[2];
    const float* W    = (const float*)d_in[3];
    const float* b    = (const float*)d_in[4];
    float* out = (float*)d_out;

    // workspace layout (~21 MB)
    unsigned short* hb = (unsigned short*)d_ws;       // NN*D bf16 (12.8 MB)
    int* binned = (int*)(hb + (size_t)NN * D);        // NBKT*BINCAP (8.0 MB)
    int* cursor = binned + NBKT * BINCAP;             // NBKT*CSTRIDE (50 KB)

    transform_kernel<<<2048, 256, 0, stream>>>(feat, W, hb, cursor);
    p2_scatter<<<NPB, 256, 0, stream>>>(src, dst, cursor, binned);
    bucket_gather<<<NBKT, 256, 0, stream>>>((const uint2*)hb, binned, cursor,
                                            b, (float4*)out);
}

// Round 2
// 161.677 us; speedup vs baseline: 1.2332x; 1.2332x over previous
//
#include <hip/hip_runtime.h>

#define NN 100000
#define NE 1600000
#define D 64
#define NBKT 782            // ceil(NN / 128) coarse buckets
#define BKT_SHIFT 7
#define BKT_MASK 127
#define SRC_MASK 0x1FFFF    // src < 100000 < 2^17
#define EPB 8192            // edges per block in P2 (196 blocks, 32 edges/thread)
#define NPB ((NE + EPB - 1) / EPB)   // 196 blocks
#define BINCAP 2560         // padded slots per bucket (mean 2048, sd ~45 -> 11 sigma)
#define TROWS 16            // rows per block iteration in transform

// float -> bf16 (round-to-nearest-even; inputs finite)
__device__ __forceinline__ unsigned short f2bf(float f) {
    unsigned u = __float_as_uint(f);
    unsigned r = u + 0x7FFF + ((u >> 16) & 1);
    return (unsigned short)(r >> 16);
}

__device__ __forceinline__ int cmp4(const int4& v, int k) {
    return k == 0 ? v.x : k == 1 ? v.y : k == 2 ? v.z : v.w;
}

// ---------------- A: h = bf16(feat @ W^T); also seeds p2's cursors ---------
__global__ __launch_bounds__(256) void transform_kernel(const float* __restrict__ feat,
                                                        const float* __restrict__ W,
                                                        unsigned short* __restrict__ hb,
                                                        int* __restrict__ cursor) {
    // seed per-bucket cursors (kernel completes before p2 launches)
    if (blockIdx.x < 4) {
        int i = blockIdx.x * 256 + threadIdx.x;
        if (i < NBKT) cursor[i] = i * BINCAP;
    }

    __shared__ float4 rowLds[TROWS][16];
    const int lane = threadIdx.x & 63;
    const int wv   = threadIdx.x >> 6;
    float4 wreg[16];
    const float4* __restrict__ W4 = (const float4*)W;
#pragma unroll
    for (int i = 0; i < 16; ++i) wreg[i] = W4[lane * 16 + i];

    const int nTiles = NN / TROWS;   // 6250 exact
    for (int tile = blockIdx.x; tile < nTiles; tile += gridDim.x) {
        const int rowBase = tile * TROWS;
        rowLds[threadIdx.x >> 4][threadIdx.x & 15] =
            ((const float4*)(feat + (size_t)(rowBase + (threadIdx.x >> 4)) * D))[threadIdx.x & 15];
        __syncthreads();
        float a0 = 0.f, a1 = 0.f, a2 = 0.f, a3 = 0.f;
#pragma unroll
        for (int k4 = 0; k4 < 16; ++k4) {
            const float4 w  = wreg[k4];
            const float4 r0 = rowLds[wv * 4 + 0][k4];
            const float4 r1 = rowLds[wv * 4 + 1][k4];
            const float4 r2 = rowLds[wv * 4 + 2][k4];
            const float4 r3 = rowLds[wv * 4 + 3][k4];
            a0 += r0.x * w.x + r0.y * w.y + r0.z * w.z + r0.w * w.w;
            a1 += r1.x * w.x + r1.y * w.y + r1.z * w.z + r1.w * w.w;
            a2 += r2.x * w.x + r2.y * w.y + r2.z * w.z + r2.w * w.w;
            a3 += r3.x * w.x + r3.y * w.y + r3.z * w.z + r3.w * w.w;
        }
        const size_t ob = (size_t)(rowBase + wv * 4) * D + lane;
        hb[ob]         = f2bf(a0);
        hb[ob + D]     = f2bf(a1);
        hb[ob + 2 * D] = f2bf(a2);
        hb[ob + 3 * D] = f2bf(a3);
        __syncthreads();
    }
}

// ---------------- P2 (single-pass): scatter packed edges into buckets ------
// 196 blocks x 8192 edges. int4 loads (16 independent loads/thread in flight).
// Phase 1: load all 32 (dst,src)/thread. Phase 2: LDS atomic ranking (hist
// ends holding per-bucket totals). Phase 3: reserve global bases via cursor
// atomics (packed cursors: 49 hot L2 lines — padding them was a measured
// regression, round 1). Phase 4: scattered stores; ~10.5 consecutive edges
// per (block,bucket) keeps write-allocate amplification ~1.5x.
__global__ __launch_bounds__(256) void p2_scatter(const int* __restrict__ src,
                                                  const int* __restrict__ dst,
                                                  int* __restrict__ cursor,
                                                  int* __restrict__ binned) {
    __shared__ int hist[NBKT];
    __shared__ int base[NBKT];
    for (int i = threadIdx.x; i < NBKT; i += 256) hist[i] = 0;
    __syncthreads();

    const int4* __restrict__ src4 = (const int4*)src;
    const int4* __restrict__ dst4 = (const int4*)dst;
    const int qlo = blockIdx.x * (EPB / 4);    // int4 index base
    const int nq  = NE / 4;                    // 400000, exact

    int4 sv[8], dv[8];
    int  rk[8][4];
#pragma unroll
    for (int it = 0; it < 8; ++it) {
        const int idx = qlo + it * 256 + threadIdx.x;
        if (idx < nq) { sv[it] = src4[idx]; dv[it] = dst4[idx]; }
        else { sv[it] = make_int4(0, 0, 0, 0); dv[it] = make_int4(-1, -1, -1, -1); }
    }
#pragma unroll
    for (int it = 0; it < 8; ++it)
#pragma unroll
        for (int k = 0; k < 4; ++k) {
            const int d = cmp4(dv[it], k);
            if (d >= 0) rk[it][k] = atomicAdd(&hist[d >> BKT_SHIFT], 1);
        }
    __syncthreads();

    for (int i = threadIdx.x; i < NBKT; i += 256) {
        const int c = hist[i];
        base[i] = c ? atomicAdd(&cursor[i], c) : 0;
    }
    __syncthreads();

#pragma unroll
    for (int it = 0; it < 8; ++it)
#pragma unroll
        for (int k = 0; k < 4; ++k) {
            const int d = cmp4(dv[it], k);
            if (d >= 0) {
                const int s = cmp4(sv[it], k);
                binned[base[d >> BKT_SHIFT] + rk[it][k]] =
                    s | ((d & BKT_MASK) << 17);
            }
        }
}

// ---------------- bucket_gather v2: counting-sort + register accumulate ----
// Per block (one 128-node bucket): counting-sort the ~2048 packed edges by
// dst-low into per-node contiguous segments in LDS (2K LDS atomics instead of
// 102M).  Then each 16-lane quarter-wave owns one node at a time and
// accumulates its 64 columns as 4 fp32 registers per lane — zero ds_add, and
// the epilogue is a direct coalesced float4 store with bias.
__global__ __launch_bounds__(256) void bucket_gather(const uint2* __restrict__ hb2,
                                                     const int* __restrict__ binned,
                                                     const int* __restrict__ cursor,
                                                     const float* __restrict__ bias,
                                                     float4* __restrict__ out4) {
    __shared__ int cnt[128];     // per-node in-degree (totals after ranking)
    __shared__ int pre[128];     // inclusive scan of cnt
    __shared__ int sEdge[BINCAP];// src indices, sorted by dst-low
    const int t = threadIdx.x;
    const int b = blockIdx.x;
    if (t < 128) cnt[t] = 0;
    __syncthreads();

    const int gbase = b * BINCAP;
    int sz = cursor[b] - gbase;
    if (sz > BINCAP) sz = BINCAP;    // 11-sigma guard

    // ---- rank edges per node (counting sort pass 1) ----
    int pk[10], dd[10], rr[10];      // BINCAP/256 == 10
#pragma unroll
    for (int it = 0; it < 10; ++it) {
        const int e = it * 256 + t;
        if (e < sz) {
            const int p = binned[gbase + e];
            dd[it] = (p >> 17) & BKT_MASK;
            pk[it] = p & SRC_MASK;
            rr[it] = atomicAdd(&cnt[dd[it]], 1);
        } else dd[it] = -1;
    }
    __syncthreads();

    // ---- inclusive scan of cnt[128] (Hillis-Steele) ----
    if (t < 128) pre[t] = cnt[t];
    __syncthreads();
    for (int s = 1; s < 128; s <<= 1) {
        int v = 0;
        if (t < 128 && t >= s) v = pre[t - s];
        __syncthreads();
        if (t < 128) pre[t] += v;
        __syncthreads();
    }

    // ---- scatter into per-node segments: node d owns [pre[d]-cnt[d], pre[d]) ----
#pragma unroll
    for (int it = 0; it < 10; ++it) {
        if (dd[it] >= 0)
            sEdge[pre[dd[it]] - cnt[dd[it]] + rr[it]] = pk[it];
    }
    __syncthreads();

    // ---- accumulate: quarter-wave per node, 4 fp32 cols per lane, unroll 4 ----
    const int q  = t >> 4;           // 16 quarters; quarter q owns nodes q*8..q*8+7
    const int c4 = t & 15;           // 8-byte column group (4 bf16 cols)
    const float4 bv = ((const float4*)bias)[c4];
    for (int i = 0; i < 8; ++i) {
        const int n    = q * 8 + i;
        const int node = b * 128 + n;
        if (node >= NN) break;       // uniform within quarter
        const int end = pre[n];
        int e = end - cnt[n];
        float a00=0.f,a01=0.f,a02=0.f,a03=0.f, a10=0.f,a11=0.f,a12=0.f,a13=0.f;
        float a20=0.f,a21=0.f,a22=0.f,a23=0.f, a30=0.f,a31=0.f,a32=0.f,a33=0.f;
        for (; e + 4 <= end; e += 4) {
            const int s0 = sEdge[e+0], s1 = sEdge[e+1], s2 = sEdge[e+2], s3 = sEdge[e+3];
            const uint2 x0 = hb2[(size_t)s0 * 16 + c4];
            const uint2 x1 = hb2[(size_t)s1 * 16 + c4];
            const uint2 x2 = hb2[(size_t)s2 * 16 + c4];
            const uint2 x3 = hb2[(size_t)s3 * 16 + c4];
            a00 += __uint_as_float(x0.x << 16); a01 += __uint_as_float(x0.x & 0xFFFF0000u);
            a02 += __uint_as_float(x0.y << 16); a03 += __uint_as_float(x0.y & 0xFFFF0000u);
            a10 += __uint_as_float(x1.x << 16); a11 += __uint_as_float(x1.x & 0xFFFF0000u);
            a12 += __uint_as_float(x1.y << 16); a13 += __uint_as_float(x1.y & 0xFFFF0000u);
            a20 += __uint_as_float(x2.x << 16); a21 += __uint_as_float(x2.x & 0xFFFF0000u);
            a22 += __uint_as_float(x2.y << 16); a23 += __uint_as_float(x2.y & 0xFFFF0000u);
            a30 += __uint_as_float(x3.x << 16); a31 += __uint_as_float(x3.x & 0xFFFF0000u);
            a32 += __uint_as_float(x3.y << 16); a33 += __uint_as_float(x3.y & 0xFFFF0000u);
        }
        for (; e < end; ++e) {
            const int s0 = sEdge[e];
            const uint2 x0 = hb2[(size_t)s0 * 16 + c4];
            a00 += __uint_as_float(x0.x << 16); a01 += __uint_as_float(x0.x & 0xFFFF0000u);
            a02 += __uint_as_float(x0.y << 16); a03 += __uint_as_float(x0.y & 0xFFFF0000u);
        }
        float4 v;
        v.x = (a00 + a10) + (a20 + a30) + bv.x;
        v.y = (a01 + a11) + (a21 + a31) + bv.y;
        v.z = (a02 + a12) + (a22 + a32) + bv.z;
        v.w = (a03 + a13) + (a23 + a33) + bv.w;
        out4[(size_t)node * 16 + c4] = v;
    }
}

extern "C" void kernel_launch(void* const* d_in, const int* in_sizes, int n_in,
                              void* d_out, int out_size, void* d_ws, size_t ws_size,
                              hipStream_t stream) {
    const float* feat = (const float*)d_in[0];
    const int*   src  = (const int*)d_in[1];
    const int*   dst  = (const int*)d_in[2];
    const float* W    = (const float*)d_in[3];
    const float* b    = (const float*)d_in[4];
    float* out = (float*)d_out;

    // workspace layout (~21 MB)
    unsigned short* hb = (unsigned short*)d_ws;       // NN*D bf16 (12.8 MB)
    int* binned = (int*)(hb + (size_t)NN * D);        // NBKT*BINCAP (8.0 MB)
    int* cursor = binned + NBKT * BINCAP;             // NBKT

    transform_kernel<<<2048, 256, 0, stream>>>(feat, W, hb, cursor);
    p2_scatter<<<NPB, 256, 0, stream>>>(src, dst, cursor, binned);
    bucket_gather<<<NBKT, 256, 0, stream>>>((const uint2*)hb, binned, cursor,
                                            b, (float4*)out);
}

// Round 4
// 152.033 us; speedup vs baseline: 1.3114x; 1.0634x over previous
//
#include <hip/hip_runtime.h>

#define NN 100000
#define NE 1600000
#define D 64
#define BKT_SHIFT 6
#define BKT_NODES 64
#define BKT_MASK 63
#define NBKT 1563           // ceil(NN / 64) buckets of 64 nodes
#define SRC_MASK 0x1FFFF    // src < 100000 < 2^17
#define EPB 8192            // edges per p2 block (196 blocks, 32 edges/thread)
#define NPB ((NE + EPB - 1) / EPB)   // 196
#define BINCAP 1280         // mean 1024, sd ~32 -> 8 sigma (fixed seed: max ~1150)
#define TROWS 16            // rows per transform tile
#define TGRID 2048          // transform blocks inside fused kernel

// float -> bf16 (round-to-nearest-even; inputs finite)
__device__ __forceinline__ unsigned short f2bf(float f) {
    unsigned u = __float_as_uint(f);
    unsigned r = u + 0x7FFF + ((u >> 16) & 1);
    return (unsigned short)(r >> 16);
}

__device__ __forceinline__ int cmp4(const int4& v, int k) {
    return k == 0 ? v.x : k == 1 ? v.y : k == 2 ? v.z : v.w;
}

// ---------------- seed: zero per-bucket cursors (no stream memset: ---------
// hipMemsetAsync inside kernel_launch is a graph-capture suspect)
__global__ __launch_bounds__(256) void seed_cursor(int* __restrict__ cursor) {
    const int i = blockIdx.x * 256 + threadIdx.x;
    if (i < NBKT) cursor[i] = 0;
}

// ---------------- fused: p2 scatter (blocks < NPB) + transform (rest) ------
// transform and p2 are fully independent (feat/W -> hb  vs  src/dst -> binned)
// so they share one launch: p2's 196 under-occupying blocks overlap with
// transform's 2048.  cursor[] holds pure per-bucket counts; binned base =
// bucket*BINCAP + count.
__global__ __launch_bounds__(256) void fused_tp2(const float* __restrict__ feat,
                                                 const float* __restrict__ W,
                                                 unsigned short* __restrict__ hb,
                                                 const int* __restrict__ src,
                                                 const int* __restrict__ dst,
                                                 int* __restrict__ cursor,
                                                 int* __restrict__ binned) {
    __shared__ int hist[NBKT];           // p2: rank counters, then bases (in-place)
    __shared__ float4 rowLds[TROWS][16]; // transform: staged rows

    if (blockIdx.x < NPB) {
        // ---------------- p2 ----------------
        for (int i = threadIdx.x; i < NBKT; i += 256) hist[i] = 0;
        __syncthreads();

        const int4* __restrict__ src4 = (const int4*)src;
        const int4* __restrict__ dst4 = (const int4*)dst;
        const int qlo = blockIdx.x * (EPB / 4);
        const int nq  = NE / 4;          // 400000, exact

        int4 dv[8];
        int  rk[8][4];
#pragma unroll
        for (int it = 0; it < 8; ++it) {
            const int idx = qlo + it * 256 + threadIdx.x;
            dv[it] = (idx < nq) ? dst4[idx] : make_int4(-1, -1, -1, -1);
        }
#pragma unroll
        for (int it = 0; it < 8; ++it)
#pragma unroll
            for (int k = 0; k < 4; ++k) {
                const int d = cmp4(dv[it], k);
                if (d >= 0) rk[it][k] = atomicAdd(&hist[d >> BKT_SHIFT], 1);
            }
        __syncthreads();

        // reserve global ranges; hist becomes base (packed cursors: 98 hot
        // L2 lines — padding them was a measured regression, round 1)
        for (int i = threadIdx.x; i < NBKT; i += 256) {
            const int c = hist[i];
            int base = i * BINCAP;
            if (c) base += atomicAdd(&cursor[i], c);
            hist[i] = base;
        }
        __syncthreads();

#pragma unroll
        for (int it = 0; it < 8; ++it) {
            const int idx = qlo + it * 256 + threadIdx.x;
            if (idx < nq) {
                const int4 s4 = src4[idx];
#pragma unroll
                for (int k = 0; k < 4; ++k) {
                    const int d = cmp4(dv[it], k);
                    const int s = cmp4(s4, k);
                    binned[hist[d >> BKT_SHIFT] + rk[it][k]] =
                        s | ((d & BKT_MASK) << 17);
                }
            }
        }
    } else {
        // ---------------- transform: h = bf16(feat @ W^T) ----------------
        const int bid  = blockIdx.x - NPB;
        const int lane = threadIdx.x & 63;
        const int wv   = threadIdx.x >> 6;
        float4 wreg[16];
        const float4* __restrict__ W4 = (const float4*)W;
#pragma unroll
        for (int i = 0; i < 16; ++i) wreg[i] = W4[lane * 16 + i];

        const int nTiles = NN / TROWS;   // 6250 exact
        for (int tile = bid; tile < nTiles; tile += TGRID) {
            const int rowBase = tile * TROWS;
            rowLds[threadIdx.x >> 4][threadIdx.x & 15] =
                ((const float4*)(feat + (size_t)(rowBase + (threadIdx.x >> 4)) * D))[threadIdx.x & 15];
            __syncthreads();
            float a0 = 0.f, a1 = 0.f, a2 = 0.f, a3 = 0.f;
#pragma unroll
            for (int k4 = 0; k4 < 16; ++k4) {
                const float4 w  = wreg[k4];
                const float4 r0 = rowLds[wv * 4 + 0][k4];
                const float4 r1 = rowLds[wv * 4 + 1][k4];
                const float4 r2 = rowLds[wv * 4 + 2][k4];
                const float4 r3 = rowLds[wv * 4 + 3][k4];
                a0 += r0.x * w.x + r0.y * w.y + r0.z * w.z + r0.w * w.w;
                a1 += r1.x * w.x + r1.y * w.y + r1.z * w.z + r1.w * w.w;
                a2 += r2.x * w.x + r2.y * w.y + r2.z * w.z + r2.w * w.w;
                a3 += r3.x * w.x + r3.y * w.y + r3.z * w.z + r3.w * w.w;
            }
            const size_t ob = (size_t)(rowBase + wv * 4) * D + lane;
            hb[ob]         = f2bf(a0);
            hb[ob + D]     = f2bf(a1);
            hb[ob + 2 * D] = f2bf(a2);
            hb[ob + 3 * D] = f2bf(a3);
            __syncthreads();
        }
    }
}

// ---------------- bucket_gather v3: 64-node buckets, unroll 8 --------------
// 1563 blocks (~6/CU).  Counting-sort ~1024 edges into per-node segments
// (single-wave shfl scan, 1 barrier), then quarter-wave per node with 8
// independent 8 B gather loads in flight per lane; fp32 register accumulate,
// coalesced float4 store with bias.
__global__ __launch_bounds__(256) void bucket_gather(const uint2* __restrict__ hb2,
                                                     const int* __restrict__ binned,
                                                     const int* __restrict__ cursor,
                                                     const float* __restrict__ bias,
                                                     float4* __restrict__ out4) {
    __shared__ int cnt[BKT_NODES];
    __shared__ int pre[BKT_NODES];
    __shared__ int sEdge[BINCAP];
    const int t = threadIdx.x;
    const int b = blockIdx.x;
    if (t < BKT_NODES) cnt[t] = 0;
    __syncthreads();

    const int gbase = b * BINCAP;
    int sz = cursor[b];
    if (sz > BINCAP) sz = BINCAP;    // guard

    // rank edges per node
    int pk[5], dd[5], rr[5];         // BINCAP/256 == 5
#pragma unroll
    for (int it = 0; it < 5; ++it) {
        const int e = it * 256 + t;
        if (e < sz) {
            const int p = binned[gbase + e];
            dd[it] = (p >> 17) & BKT_MASK;
            pk[it] = p & SRC_MASK;
            rr[it] = atomicAdd(&cnt[dd[it]], 1);
        } else dd[it] = -1;
    }
    __syncthreads();

    // inclusive scan of cnt[64] entirely inside wave 0
    if (t < 64) {
        int v = cnt[t];
#pragma unroll
        for (int s = 1; s < 64; s <<= 1) {
            const int u = __shfl_up(v, s);
            if (t >= s) v += u;
        }
        pre[t] = v;
    }
    __syncthreads();

    // scatter into per-node segments: node d owns [pre[d]-cnt[d], pre[d])
#pragma unroll
    for (int it = 0; it < 5; ++it) {
        if (dd[it] >= 0)
            sEdge[pre[dd[it]] - cnt[dd[it]] + rr[it]] = pk[it];
    }
    __syncthreads();

    // accumulate: quarter-wave per node, 4 fp32 cols per lane, 8 loads in flight
    const int q  = t >> 4;           // 16 quarters; quarter q owns nodes q*4..q*4+3
    const int c4 = t & 15;           // 8-byte column group (4 bf16 cols)
    const float4 bv = ((const float4*)bias)[c4];
#pragma unroll
    for (int i = 0; i < 4; ++i) {
        const int n    = q * 4 + i;
        const int node = b * BKT_NODES + n;
        if (node >= NN) break;       // uniform within quarter
        const int end = pre[n];
        float ax = 0.f, ay = 0.f, az = 0.f, aw = 0.f;
        for (int e = end - cnt[n]; e < end; e += 8) {
            uint2 x[8];
#pragma unroll
            for (int j = 0; j < 8; ++j) {
                const int idx = (e + j < end) ? sEdge[e + j] : -1;
                x[j] = (idx >= 0) ? hb2[(size_t)idx * 16 + c4] : make_uint2(0u, 0u);
            }
#pragma unroll
            for (int j = 0; j < 8; ++j) {
                ax += __uint_as_float(x[j].x << 16);
                ay += __uint_as_float(x[j].x & 0xFFFF0000u);
                az += __uint_as_float(x[j].y << 16);
                aw += __uint_as_float(x[j].y & 0xFFFF0000u);
            }
        }
        float4 v;
        v.x = ax + bv.x; v.y = ay + bv.y; v.z = az + bv.z; v.w = aw + bv.w;
        out4[(size_t)node * 16 + c4] = v;
    }
}

extern "C" void kernel_launch(void* const* d_in, const int* in_sizes, int n_in,
                              void* d_out, int out_size, void* d_ws, size_t ws_size,
                              hipStream_t stream) {
    const float* feat = (const float*)d_in[0];
    const int*   src  = (const int*)d_in[1];
    const int*   dst  = (const int*)d_in[2];
    const float* W    = (const float*)d_in[3];
    const float* b    = (const float*)d_in[4];
    float* out = (float*)d_out;

    // workspace layout (~20.8 MB)
    unsigned short* hb = (unsigned short*)d_ws;       // NN*D bf16 (12.8 MB)
    int* binned = (int*)(hb + (size_t)NN * D);        // NBKT*BINCAP (8.0 MB)
    int* cursor = binned + NBKT * BINCAP;             // NBKT counts

    seed_cursor<<<(NBKT + 255) / 256, 256, 0, stream>>>(cursor);
    fused_tp2<<<NPB + TGRID, 256, 0, stream>>>(feat, W, hb, src, dst, cursor, binned);
    bucket_gather<<<NBKT, 256, 0, stream>>>((const uint2*)hb, binned, cursor,
                                            b, (float4*)out);
}